// Round 1
// baseline (283.065 us; speedup 1.0000x reference)
//
#include <hip/hip_runtime.h>

// CRF forward (log-partition minus gold score), B=2048, L=512, T=32.
// One batch element per 32-lane group (2 per wave64). Scaled linear-space
// forward: a[j] <- (sum_i a[i]*E[i][j]) * exp(emit[t][j]),  E = exp(trans).
// Renorm by lane-0 alpha every 4 steps; logz = (log2(sum a) + LS) * ln2.

constexpr int TT = 32;   // tags
constexpr int LL = 512;  // seq len

#define L2E  1.4426950408889634f
#define LN2f 0.6931471805599453f

template<int I>
__device__ __forceinline__ float bcastf(float v) {
  // broadcast lane I within each 32-lane group (BitMode: and=0, or=I)
  return __int_as_float(__builtin_amdgcn_ds_swizzle(__float_as_int(v), (I << 5)));
}
template<int X>
__device__ __forceinline__ float swzxf(float v) {
  // lane ^ X within each 32-lane group (BitMode: and=0x1F, xor=X)
  return __int_as_float(__builtin_amdgcn_ds_swizzle(__float_as_int(v), (X << 10) | 0x1F));
}
__device__ __forceinline__ float bpermf(int byteaddr, float v) {
  return __int_as_float(__builtin_amdgcn_ds_bpermute(byteaddr, __float_as_int(v)));
}

// 4 i-steps of the matvec: acc += a[i] * E[i][j], broadcasts via ds_swizzle
#define MV4(i0) do { \
    float av0 = bcastf<(i0)>(a);     float av1 = bcastf<(i0)+1>(a); \
    float av2 = bcastf<(i0)+2>(a);   float av3 = bcastf<(i0)+3>(a); \
    acc0 = fmaf(av0, Ec[(i0)],   acc0); acc1 = fmaf(av1, Ec[(i0)+1], acc1); \
    acc2 = fmaf(av2, Ec[(i0)+2], acc2); acc3 = fmaf(av3, Ec[(i0)+3], acc3); \
  } while (0)

__global__ __launch_bounds__(256, 1) void crf_fwd(
    const float* __restrict__ emit, const float* __restrict__ trans,
    const int* __restrict__ tags, const int* __restrict__ lengths,
    float* __restrict__ out, int B)
{
  __shared__ float s_trans[TT * TT];
  {
    // 256 threads x float4 = 1024 floats
    const float4* t4 = (const float4*)trans;
    ((float4*)s_trans)[threadIdx.x] = t4[threadIdx.x];
  }
  __syncthreads();

  const int lane = threadIdx.x & 31;
  const int b = blockIdx.x * (blockDim.x >> 5) + (threadIdx.x >> 5);
  if (b >= B) return;
  const int gbase4 = (threadIdx.x & 32) << 2;  // byte offset of this group's lane 0

  // E columns in registers: Ec[i] = exp(trans[i][lane])
  float Ec[TT];
#pragma unroll
  for (int i = 0; i < TT; ++i)
    Ec[i] = __builtin_amdgcn_exp2f(s_trans[i * TT + lane] * L2E);

  const int len = lengths[b];
  const float* erow = emit + (size_t)b * (LL * TT);
  const int*  trow = tags + (size_t)b * LL;

  // t = 0 prologue
  float e0  = erow[lane];
  int  ptag = trow[0];
  float g   = bpermf((ptag << 2) + gbase4, e0);     // gold += emit[0][tag0]
  float a   = __builtin_amdgcn_exp2f(e0 * L2E);     // alpha in linear space
  float LS  = 0.f;                                  // accumulated log2 scale

  // wave-uniform loop bound = max over the wave's two batches
  int mlen = max(len, __shfl_xor(len, 32));
  mlen = __builtin_amdgcn_readfirstlane(mlen);
  const int nch = (mlen - 1 + 3) >> 2;   // 4-step chunks

  // software pipeline: current chunk (eb/tg), next (en/tgn), prefetch 2 ahead
  float eb[4], en[4];
  int   tg[4], tgn[4];
#pragma unroll
  for (int k = 0; k < 4; ++k) {
    int t = 1 + k; int tc = t < LL ? t : LL - 1;
    eb[k] = erow[tc * TT + lane];
    tg[k] = trow[tc];
  }
#pragma unroll
  for (int k = 0; k < 4; ++k) {
    int t = 5 + k; int tc = t < LL ? t : LL - 1;
    en[k] = erow[tc * TT + lane];
    tgn[k] = trow[tc];
  }

  for (int c = 0; c < nch; ++c) {
    const int tb = 1 + (c << 2);

    // prefetch chunk c+2 (clamped)
    float ep[4]; int tgp[4];
#pragma unroll
    for (int k = 0; k < 4; ++k) {
      int t = tb + 8 + k; int tc = t < LL ? t : LL - 1;
      ep[k]  = erow[tc * TT + lane];
      tgp[k] = trow[tc];
    }

    // exp(emit) for the whole current chunk up front (off critical path)
    float e2v[4];
#pragma unroll
    for (int k = 0; k < 4; ++k) e2v[k] = __builtin_amdgcn_exp2f(eb[k] * L2E);

#pragma unroll
    for (int k = 0; k < 4; ++k) {
      const int t = tb + k;
      float acc0 = 0.f, acc1 = 0.f, acc2 = 0.f, acc3 = 0.f;
      MV4(0); MV4(4); MV4(8); MV4(12); MV4(16); MV4(20); MV4(24); MV4(28);
      float anew = ((acc0 + acc1) + (acc2 + acc3)) * e2v[k];
      const bool valid = t < len;
      a = valid ? anew : a;

      // gold score: emit[t][tag_t] + trans[tag_{t-1}][tag_t]
      int tag  = tg[k];
      float eg = bpermf((tag << 2) + gbase4, eb[k]);
      float tr = s_trans[(ptag << 5) + tag];
      g += valid ? (eg + tr) : 0.f;
      ptag = tag;
    }

    // cheap renorm: scale by lane-0 alpha (logz-invariant, safe for masked groups)
    float m = fmaxf(bcastf<0>(a), 1e-30f);
    float r = __builtin_amdgcn_rcpf(m);
    a *= r;
    LS += __builtin_amdgcn_logf(m);   // v_log_f32 = log2

    // rotate pipeline buffers
#pragma unroll
    for (int k = 0; k < 4; ++k) {
      eb[k] = en[k]; tg[k] = tgn[k];
      en[k] = ep[k]; tgn[k] = tgp[k];
    }
  }

  // log_z = (log2(sum_j a) + LS) * ln2 ; out = log_z - gold
  float s = a;
  s += swzxf<1>(s); s += swzxf<2>(s); s += swzxf<4>(s);
  s += swzxf<8>(s); s += swzxf<16>(s);
  float logz = (__builtin_amdgcn_logf(s) + LS) * LN2f;
  if (lane == 0) out[b] = logz - g;
}

extern "C" void kernel_launch(void* const* d_in, const int* in_sizes, int n_in,
                              void* d_out, int out_size, void* d_ws, size_t ws_size,
                              hipStream_t stream) {
  const float* emit    = (const float*)d_in[0];
  const float* trans   = (const float*)d_in[1];
  const int*   tags    = (const int*)d_in[2];
  const int*   lengths = (const int*)d_in[3];
  float*       out     = (float*)d_out;
  const int B = in_sizes[3];             // lengths is (B,)
  const int groupsPerBlock = 256 / 32;   // 8 batches per block
  const int blocks = (B + groupsPerBlock - 1) / groupsPerBlock;
  hipLaunchKernelGGL(crf_fwd, dim3(blocks), dim3(256), 0, stream,
                     emit, trans, tags, lengths, out, B);
}

// Round 2
// 273.183 us; speedup vs baseline: 1.0362x; 1.0362x over previous
//
#include <hip/hip_runtime.h>

// CRF forward (log-partition minus gold score), B=2048, L=512, T=32.
// One batch per 32-lane group, 2 per wave64, ONE wave per block (1024 blocks
// -> scheduler load-balances the length tail). Scaled linear-space forward:
//   a[j] <- (sum_i a[i]*E[i][j]) * exp(emit[t][j]),  E = exp(trans)
// Alpha broadcast per step via 1 ds_write_b32 + 8 same-address ds_read_b128
// (LDS broadcast, conflict-free) instead of 32 ds_swizzles (R1 was LDS-pipe
// throughput bound: VALUBusy 15%).

constexpr int TT = 32;   // tags
constexpr int LL = 512;  // seq len

#define L2E  1.4426950408889634f
#define LN2f 0.6931471805599453f

template<int I>
__device__ __forceinline__ float bcastf(float v) {
  // broadcast lane I within each 32-lane group (BitMode: and=0, or=I)
  return __int_as_float(__builtin_amdgcn_ds_swizzle(__float_as_int(v), (I << 5)));
}
template<int X>
__device__ __forceinline__ float swzxf(float v) {
  // lane ^ X within each 32-lane group (BitMode: and=0x1F, xor=X)
  return __int_as_float(__builtin_amdgcn_ds_swizzle(__float_as_int(v), (X << 10) | 0x1F));
}

__global__ __launch_bounds__(64) void crf_fwd(
    const float* __restrict__ emit, const float* __restrict__ trans,
    const int* __restrict__ tags, const int* __restrict__ lengths,
    float* __restrict__ out, int B)
{
  __shared__ float  s_trans[TT * TT];
  __shared__ float4 s_alpha[2][TT / 4];   // per-group alpha broadcast buffer

  {
    // 64 threads x 4 float4 = 1024 floats
    const float4* t4 = (const float4*)trans;
    float4* st4 = (float4*)s_trans;
#pragma unroll
    for (int k = 0; k < 4; ++k)
      st4[threadIdx.x + 64 * k] = t4[threadIdx.x + 64 * k];
  }
  __syncthreads();

  const int lane = threadIdx.x & 31;
  const int grp  = threadIdx.x >> 5;
  const int b = blockIdx.x * 2 + grp;
  if (b >= B) return;
  float* sa = (float*)&s_alpha[grp][0];

  // E columns in registers: Ec[i] = exp(trans[i][lane])
  float Ec[TT];
#pragma unroll
  for (int i = 0; i < TT; ++i)
    Ec[i] = __builtin_amdgcn_exp2f(s_trans[i * TT + lane] * L2E);

  const int len = lengths[b];
  const float* erow = emit + (size_t)b * (LL * TT);
  const int*  trow  = tags + (size_t)b * LL;

  // t = 0 prologue
  float e0   = erow[lane];
  int   ptag = trow[0];
  float a    = __builtin_amdgcn_exp2f(e0 * L2E);  // alpha, linear space
  float gacc = (lane == ptag) ? e0 : 0.f;         // per-lane gold accumulator
  float LS   = 0.f;                               // accumulated log2 scale

  // wave-uniform loop bound = max over the wave's two batches
  int mlen = max(len, __shfl_xor(len, 32));
  mlen = __builtin_amdgcn_readfirstlane(mlen);
  const int nch = (mlen - 1 + 3) >> 2;   // 4-step chunks

  // software pipeline: current chunk (eb/tg), next (en/tgn), prefetch 2 ahead
  float eb[4], en[4];
  int   tg[4], tgn[4];
#pragma unroll
  for (int k = 0; k < 4; ++k) {
    int t = 1 + k; int tc = t < LL ? t : LL - 1;
    eb[k] = erow[tc * TT + lane];
    tg[k] = trow[tc];
  }
#pragma unroll
  for (int k = 0; k < 4; ++k) {
    int t = 5 + k; int tc = t < LL ? t : LL - 1;
    en[k] = erow[tc * TT + lane];
    tgn[k] = trow[tc];
  }

  for (int c = 0; c < nch; ++c) {
    const int tb = 1 + (c << 2);

    // prefetch chunk c+2 (clamped)
    float ep[4]; int tgp[4];
#pragma unroll
    for (int k = 0; k < 4; ++k) {
      int t = tb + 8 + k; int tc = t < LL ? t : LL - 1;
      ep[k]  = erow[tc * TT + lane];
      tgp[k] = trow[tc];
    }

    // exp(emit) for the whole chunk up front (off critical path)
    float e2v[4];
#pragma unroll
    for (int k = 0; k < 4; ++k) e2v[k] = __builtin_amdgcn_exp2f(eb[k] * L2E);

#pragma unroll
    for (int k = 0; k < 4; ++k) {
      const int t = tb + k;

      // publish current alpha, then read the whole vector back (broadcast)
      sa[lane] = a;
      float4 A[8];
#pragma unroll
      for (int q = 0; q < 8; ++q) A[q] = s_alpha[grp][q];

      float acc0 = 0.f, acc1 = 0.f, acc2 = 0.f, acc3 = 0.f;
#pragma unroll
      for (int q = 0; q < 8; ++q) {
        acc0 = fmaf(A[q].x, Ec[4 * q + 0], acc0);
        acc1 = fmaf(A[q].y, Ec[4 * q + 1], acc1);
        acc2 = fmaf(A[q].z, Ec[4 * q + 2], acc2);
        acc3 = fmaf(A[q].w, Ec[4 * q + 3], acc3);
      }
      float anew = ((acc0 + acc1) + (acc2 + acc3)) * e2v[k];
      const bool valid = t < len;
      a = valid ? anew : a;

      // gold: lane==tag accumulates emit[t][tag] + trans[ptag][tag]
      int tag  = tg[k];
      float tr = s_trans[(ptag << 5) + lane];   // stride-1, conflict-free
      gacc += ((lane == tag) && valid) ? (eb[k] + tr) : 0.f;
      ptag = tag;
    }

    // cheap renorm: scale by lane-0 alpha (logz-invariant, safe when masked)
    float m = fmaxf(bcastf<0>(a), 1e-30f);
    float r = __builtin_amdgcn_rcpf(m);
    a *= r;
    LS += __builtin_amdgcn_logf(m);   // v_log_f32 = log2

    // rotate pipeline buffers
#pragma unroll
    for (int k = 0; k < 4; ++k) {
      eb[k] = en[k]; tg[k] = tgn[k];
      en[k] = ep[k]; tgn[k] = tgp[k];
    }
  }

  // reduce alpha-sum and gold-sum across the 32-lane group
  float s  = a;
  float gs = gacc;
  s += swzxf<1>(s);   gs += swzxf<1>(gs);
  s += swzxf<2>(s);   gs += swzxf<2>(gs);
  s += swzxf<4>(s);   gs += swzxf<4>(gs);
  s += swzxf<8>(s);   gs += swzxf<8>(gs);
  s += swzxf<16>(s);  gs += swzxf<16>(gs);

  float logz = (__builtin_amdgcn_logf(s) + LS) * LN2f;
  if (lane == 0) out[b] = logz - gs;
}

extern "C" void kernel_launch(void* const* d_in, const int* in_sizes, int n_in,
                              void* d_out, int out_size, void* d_ws, size_t ws_size,
                              hipStream_t stream) {
  const float* emit    = (const float*)d_in[0];
  const float* trans   = (const float*)d_in[1];
  const int*   tags    = (const int*)d_in[2];
  const int*   lengths = (const int*)d_in[3];
  float*       out     = (float*)d_out;
  const int B = in_sizes[3];             // lengths is (B,)
  const int blocks = (B + 1) / 2;        // 1 wave (2 batches) per block
  hipLaunchKernelGGL(crf_fwd, dim3(blocks), dim3(64), 0, stream,
                     emit, trans, tags, lengths, out, B);
}